// Round 2
// baseline (476.681 us; speedup 1.0000x reference)
//
#include <hip/hip_runtime.h>
#include <hip/hip_bf16.h>

// Problem constants
#define B_DIM   512
#define IN_DIM  4096
#define OUT_DIM 11008

typedef __bf16 bf16x4 __attribute__((ext_vector_type(4)));
typedef __bf16 bf16x8 __attribute__((ext_vector_type(8)));
typedef float  floatx4 __attribute__((ext_vector_type(4)));

// ---------------------------------------------------------------------------
// x fp32 -> bf16 (4 MB ws traffic; ~3 us)
// ---------------------------------------------------------------------------
__global__ __launch_bounds__(256) void conv_x_kernel(
    const float* __restrict__ x, __bf16* __restrict__ xb) {
  int idx = blockIdx.x * blockDim.x + threadIdx.x;  // quad index
  float4 v = ((const float4*)x)[idx];
  bf16x4 o;
  o[0] = (__bf16)v.x; o[1] = (__bf16)v.y; o[2] = (__bf16)v.z; o[3] = (__bf16)v.w;
  ((bf16x4*)xb)[idx] = o;
}

__device__ __forceinline__ void gl_lds16(const __bf16* g, __bf16* l) {
  __builtin_amdgcn_global_load_lds(
      (const __attribute__((address_space(1))) void*)g,
      (__attribute__((address_space(3))) void*)l, 16, 0, 0);
}

// ---------------------------------------------------------------------------
// Fused decode + GEMM.
// C(512 x 11008) = A(512x4096, bf16) * W^T, W decoded on the fly from
// stored/sign int32 arrays (row-major [OUT][IN] = [N][K]).
// BM=512 (all of M) so each weight is read+decoded EXACTLY once.
// BN=64, BK=32, 512 threads = 8 waves; wave w owns rows [64w, 64w+64),
// all 64 cols: 4x4 grid of mfma_f32_16x16x32_bf16 (64 acc VGPRs).
// Grid = 11008/64 = 172 blocks.
// ---------------------------------------------------------------------------
__global__ __launch_bounds__(512, 2) void fused_gemm_kernel(
    const __bf16* __restrict__ A,       // 512 x 4096 bf16 (pre-converted x)
    const int* __restrict__ stored,     // 11008 x 4096 int32 in [1,255]
    const int* __restrict__ sign,       // 11008 x 4096 int32 in {-1,+1}
    const float* __restrict__ logmin, const float* __restrict__ logmax,
    const float* __restrict__ scale, const float* __restrict__ bias,
    float* __restrict__ out) {          // 512 x 11008 fp32
  constexpr int K = IN_DIM, N = OUT_DIM;
  constexpr int BK = 32;

  __shared__ __align__(16) __bf16 sA[512 * BK];  // 32 KB, row-major stride 32
  __shared__ __align__(16) __bf16 sB[64 * BK];   // 4 KB

  const int tid  = threadIdx.x;
  const int lane = tid & 63;
  const int wave = tid >> 6;          // 0..7 : m-slice (rows 64*wave ..)
  const int m16  = lane & 15;
  const int q    = lane >> 4;         // quad 0..3

  const int bn0 = blockIdx.x * 64;

  const float lmin  = logmin[0];
  const float slope = (logmax[0] - lmin) * (1.0f / 254.0f);

  // A staging: 4 global_load_lds(16B) per thread per K-step.
  // Issue j covers rows [j*128, j*128+128): thread t -> row j*128 + t/4,
  // col (t&3)*8. LDS dst = wave-uniform base + lane*16  (hw constraint ok).
  const int ar = tid >> 2;            // 0..127
  const int ac = (tid & 3) * 8;
  const __bf16* gA = A + (size_t)ar * K + ac;
  __bf16* lA = sA + tid * 8;

  // B staging: 4 weights per thread (int4 stored + int4 sign -> bf16x4).
  // Thread t -> tile row t/8 (0..63), k-offset (t&7)*4.
  const int br = tid >> 3;            // 0..63
  const int bc = (tid & 7) * 4;
  const int* gS = stored + (size_t)(bn0 + br) * K + bc;
  const int* gG = sign   + (size_t)(bn0 + br) * K + bc;
  __bf16* lB = sB + tid * 4;

  floatx4 acc[4][4] = {};

  for (int kt = 0; kt < K; kt += BK) {
    // Issue B-int loads early: in flight across the barrier.
    int4 s = *(const int4*)(gS + kt);
    int4 g = *(const int4*)(gG + kt);

    __syncthreads();                  // previous iter's frag reads done

    gl_lds16(gA + kt,             lA);
    gl_lds16(gA + kt + 128 * K,   lA + 4096);
    gl_lds16(gA + kt + 256 * K,   lA + 8192);
    gl_lds16(gA + kt + 384 * K,   lA + 12288);

    // Decode 4 weights (VALU, overlaps the async A staging).
    bf16x4 wv;
    wv[0] = (__bf16)(__expf(lmin + (float)(255 - s.x) * slope) * (float)g.x);
    wv[1] = (__bf16)(__expf(lmin + (float)(255 - s.y) * slope) * (float)g.y);
    wv[2] = (__bf16)(__expf(lmin + (float)(255 - s.z) * slope) * (float)g.z);
    wv[3] = (__bf16)(__expf(lmin + (float)(255 - s.w) * slope) * (float)g.w);
    *(bf16x4*)lB = wv;                // ds_write_b64

    __syncthreads();                  // drains vmcnt (A) + lgkm (B write)

    bf16x8 afr[4], bfr[4];
#pragma unroll
    for (int i = 0; i < 4; ++i)
      afr[i] = *(const bf16x8*)&sA[(wave * 64 + i * 16 + m16) * BK + q * 8];
#pragma unroll
    for (int i = 0; i < 4; ++i)
      bfr[i] = *(const bf16x8*)&sB[(i * 16 + m16) * BK + q * 8];

#pragma unroll
    for (int mi = 0; mi < 4; ++mi)
#pragma unroll
      for (int ni = 0; ni < 4; ++ni)
        acc[mi][ni] = __builtin_amdgcn_mfma_f32_16x16x32_bf16(
            afr[mi], bfr[ni], acc[mi][ni], 0, 0, 0);
  }

  // Epilogue. C/D layout: col = lane&15, row = q*4 + reg  [m89]
#pragma unroll
  for (int ni = 0; ni < 4; ++ni) {
    const int col = bn0 + ni * 16 + m16;
    const float sc = scale[col];
    const float bb = bias[col] * sc;
#pragma unroll
    for (int mi = 0; mi < 4; ++mi) {
#pragma unroll
      for (int r = 0; r < 4; ++r) {
        const int row = wave * 64 + mi * 16 + q * 4 + r;
        out[(size_t)row * N + col] = acc[mi][ni][r] * sc + bb;
      }
    }
  }
}

// ---------------------------------------------------------------------------
extern "C" void kernel_launch(void* const* d_in, const int* in_sizes, int n_in,
                              void* d_out, int out_size, void* d_ws, size_t ws_size,
                              hipStream_t stream) {
  const float* x      = (const float*)d_in[0];
  const int*   stored = (const int*)d_in[1];
  const int*   sign   = (const int*)d_in[2];
  const float* logmin = (const float*)d_in[3];
  const float* logmax = (const float*)d_in[4];
  const float* scale  = (const float*)d_in[5];
  const float* bias   = (const float*)d_in[6];
  float* out = (float*)d_out;

  __bf16* wsX = (__bf16*)d_ws;   // 512*4096 bf16 = 4 MB

  conv_x_kernel<<<(B_DIM * (IN_DIM / 4)) / 256, 256, 0, stream>>>(x, wsX);
  fused_gemm_kernel<<<OUT_DIM / 64, 512, 0, stream>>>(
      wsX, stored, sign, logmin, logmax, scale, bias, out);
}